// Round 1
// baseline (21151.353 us; speedup 1.0000x reference)
//
#include <hip/hip_runtime.h>

#define BB 16
#define SS 128
#define TT 128
#define EE 512
#define HH 512
#define DD 1024
#define VO 10000

__device__ __forceinline__ float wred(float s) {
#pragma unroll
  for (int off = 32; off >= 1; off >>= 1) s += __shfl_xor(s, off, 64);
  return s;
}
__device__ __forceinline__ float sigm(float x) { return 1.f / (1.f + expf(-x)); }

// ---- embedding gather (padding_idx=0 -> zeros), out layout [Sn][B][E] ----
__global__ void gather_k(const int* __restrict__ idx, const float* __restrict__ emb,
                         float* __restrict__ out, int Sn) {
  const int s = blockIdx.x, b = blockIdx.y, tid = threadIdx.x;
  const int id = idx[b * Sn + s];
  float4 v = make_float4(0.f, 0.f, 0.f, 0.f);
  if (id != 0) v = ((const float4*)(emb + (size_t)id * EE))[tid];
  ((float4*)(out + ((size_t)s * BB + b) * EE))[tid] = v;
}

// ---- encoder LSTM cell: one time step, both dirs (blockIdx.y) ----
// wave handles one hidden unit d for 8 batches; lanes split K; 4 gates in regs
template <int IN1>
__global__ void enc_cell_k(int t, const float* __restrict__ xs,
                           const float* __restrict__ wih, const float* __restrict__ whh,
                           const float* __restrict__ bias, const float* __restrict__ hprev,
                           float* __restrict__ hnew, float* __restrict__ cbuf,
                           float* __restrict__ seq, int seq_ts, int seq_bs) {
  const int lane = threadIdx.x & 63;
  const int wg = (blockIdx.x * blockDim.x + threadIdx.x) >> 6;  // 0..2*HH-1
  const int dir = blockIdx.y;
  const int d = wg >> 1;
  const int bg = (wg & 1) * 8;
  const int idx = dir ? (SS - 1 - t) : t;
  const float* x = xs + (size_t)idx * (BB * IN1);
  const float* wih_d = wih + (size_t)dir * (4 * HH * IN1);
  const float* whh_d = whh + (size_t)dir * (4 * HH * HH);
  const float* bias_d = bias + dir * (4 * HH);
  const float* hp = hprev + dir * (BB * HH);
  float* hn = hnew + dir * (BB * HH);
  float* cc = cbuf + dir * (BB * HH);

  float acc[4][8];
#pragma unroll
  for (int g = 0; g < 4; ++g)
#pragma unroll
    for (int j = 0; j < 8; ++j) acc[g][j] = 0.f;

  for (int kb = 0; kb < IN1 / 64; ++kb) {
    const int k = kb * 64 + lane;
    float xv[8];
#pragma unroll
    for (int j = 0; j < 8; ++j) xv[j] = x[(bg + j) * IN1 + k];
#pragma unroll
    for (int g = 0; g < 4; ++g) {
      const float wv = wih_d[(size_t)(g * HH + d) * IN1 + k];
#pragma unroll
      for (int j = 0; j < 8; ++j) acc[g][j] = fmaf(wv, xv[j], acc[g][j]);
    }
  }
  for (int kb = 0; kb < HH / 64; ++kb) {
    const int k = kb * 64 + lane;
    float xv[8];
#pragma unroll
    for (int j = 0; j < 8; ++j) xv[j] = hp[(bg + j) * HH + k];
#pragma unroll
    for (int g = 0; g < 4; ++g) {
      const float wv = whh_d[(size_t)(g * HH + d) * HH + k];
#pragma unroll
      for (int j = 0; j < 8; ++j) acc[g][j] = fmaf(wv, xv[j], acc[g][j]);
    }
  }
#pragma unroll
  for (int g = 0; g < 4; ++g)
#pragma unroll
    for (int j = 0; j < 8; ++j) acc[g][j] = wred(acc[g][j]);

  float s0 = 0, s1 = 0, s2 = 0, s3 = 0;
#pragma unroll
  for (int j = 0; j < 8; ++j)
    if (lane == j) { s0 = acc[0][j]; s1 = acc[1][j]; s2 = acc[2][j]; s3 = acc[3][j]; }
  if (lane < 8) {
    const int b = bg + lane;
    s0 += bias_d[d]; s1 += bias_d[HH + d]; s2 += bias_d[2 * HH + d]; s3 += bias_d[3 * HH + d];
    const float ig = sigm(s0), fg = sigm(s1), gg = tanhf(s2), og = sigm(s3);
    const float cn = fg * cc[b * HH + d] + ig * gg;
    const float hv = og * tanhf(cn);
    cc[b * HH + d] = cn;
    hn[b * HH + d] = hv;
    seq[(size_t)idx * seq_ts + (size_t)b * seq_bs + dir * HH + d] = hv;
  }
}

// ---- decoder LSTM cell (hidden DD), input = concat(x1[IN1], x2[IN2]) ----
template <int IN1, int IN2>
__global__ void dec_cell_k(const float* __restrict__ x1, const float* __restrict__ x2,
                           const float* __restrict__ hprev, float* __restrict__ hnew,
                           float* __restrict__ cbuf, const float* __restrict__ wih,
                           const float* __restrict__ whh, const float* __restrict__ bias) {
  const int lane = threadIdx.x & 63;
  const int wg = (blockIdx.x * blockDim.x + threadIdx.x) >> 6;  // 0..2*DD-1
  const int d = wg >> 1;
  const int bg = (wg & 1) * 8;
  constexpr int INW = IN1 + IN2;

  float acc[4][8];
#pragma unroll
  for (int g = 0; g < 4; ++g)
#pragma unroll
    for (int j = 0; j < 8; ++j) acc[g][j] = 0.f;

  for (int kb = 0; kb < IN1 / 64; ++kb) {
    const int k = kb * 64 + lane;
    float xv[8];
#pragma unroll
    for (int j = 0; j < 8; ++j) xv[j] = x1[(bg + j) * IN1 + k];
#pragma unroll
    for (int g = 0; g < 4; ++g) {
      const float wv = wih[(size_t)(g * DD + d) * INW + k];
#pragma unroll
      for (int j = 0; j < 8; ++j) acc[g][j] = fmaf(wv, xv[j], acc[g][j]);
    }
  }
  if constexpr (IN2 > 0) {
    for (int kb = 0; kb < IN2 / 64; ++kb) {
      const int k = kb * 64 + lane;
      float xv[8];
#pragma unroll
      for (int j = 0; j < 8; ++j) xv[j] = x2[(bg + j) * IN2 + k];
#pragma unroll
      for (int g = 0; g < 4; ++g) {
        const float wv = wih[(size_t)(g * DD + d) * INW + IN1 + k];
#pragma unroll
        for (int j = 0; j < 8; ++j) acc[g][j] = fmaf(wv, xv[j], acc[g][j]);
      }
    }
  }
  for (int kb = 0; kb < DD / 64; ++kb) {
    const int k = kb * 64 + lane;
    float xv[8];
#pragma unroll
    for (int j = 0; j < 8; ++j) xv[j] = hprev[(bg + j) * DD + k];
#pragma unroll
    for (int g = 0; g < 4; ++g) {
      const float wv = whh[(size_t)(g * DD + d) * DD + k];
#pragma unroll
      for (int j = 0; j < 8; ++j) acc[g][j] = fmaf(wv, xv[j], acc[g][j]);
    }
  }
#pragma unroll
  for (int g = 0; g < 4; ++g)
#pragma unroll
    for (int j = 0; j < 8; ++j) acc[g][j] = wred(acc[g][j]);

  float s0 = 0, s1 = 0, s2 = 0, s3 = 0;
#pragma unroll
  for (int j = 0; j < 8; ++j)
    if (lane == j) { s0 = acc[0][j]; s1 = acc[1][j]; s2 = acc[2][j]; s3 = acc[3][j]; }
  if (lane < 8) {
    const int b = bg + lane;
    s0 += bias[d]; s1 += bias[DD + d]; s2 += bias[2 * DD + d]; s3 += bias[3 * DD + d];
    const float ig = sigm(s0), fg = sigm(s1), gg = tanhf(s2), og = sigm(s3);
    const float cn = fg * cbuf[b * DD + d] + ig * gg;
    const float hv = og * tanhf(cn);
    cbuf[b * DD + d] = cn;
    hn2: ;
    hnew[b * DD + d] = hv;
  }
}

// ---- encWe[b,s,d] = sum_k enc_out[b,s,k] * attn_w[d, 1024+k]  (once) ----
__global__ void encwe_k(const float* __restrict__ enc_out, const float* __restrict__ attn_w,
                        float* __restrict__ encWe) {
  const int lane = threadIdx.x & 63;
  const int wg = (blockIdx.x * blockDim.x + threadIdx.x) >> 6;  // 0..SS*DD-1
  const int s = wg >> 10;
  const int d = wg & 1023;
  float acc[16];
#pragma unroll
  for (int b = 0; b < 16; ++b) acc[b] = 0.f;
  for (int kb = 0; kb < 16; ++kb) {
    const int k = kb * 64 + lane;
    const float wv = attn_w[(size_t)d * 2048 + 1024 + k];
#pragma unroll
    for (int b = 0; b < 16; ++b)
      acc[b] = fmaf(wv, enc_out[((size_t)(b * SS + s)) * 1024 + k], acc[b]);
  }
#pragma unroll
  for (int b = 0; b < 16; ++b) acc[b] = wred(acc[b]);
  float sel = 0.f;
#pragma unroll
  for (int b = 0; b < 16; ++b)
    if (lane == b) sel = acc[b];
  if (lane < 16) encWe[((size_t)(lane * SS + s)) * 1024 + d] = sel;
}

// ---- qW[b,d] = attn_b[d] + sum_k c1[b,k] * attn_w[d,k] ----
__global__ void qw_k(const float* __restrict__ c1, const float* __restrict__ attn_w,
                     const float* __restrict__ attn_b, float* __restrict__ qW) {
  const int lane = threadIdx.x & 63;
  const int wg = (blockIdx.x * blockDim.x + threadIdx.x) >> 6;  // 0..2*DD-1
  const int d = wg >> 1;
  const int bg = (wg & 1) * 8;
  float acc[8];
#pragma unroll
  for (int j = 0; j < 8; ++j) acc[j] = 0.f;
  for (int kb = 0; kb < 16; ++kb) {
    const int k = kb * 64 + lane;
    const float wv = attn_w[(size_t)d * 2048 + k];
#pragma unroll
    for (int j = 0; j < 8; ++j) acc[j] = fmaf(wv, c1[(bg + j) * DD + k], acc[j]);
  }
#pragma unroll
  for (int j = 0; j < 8; ++j) acc[j] = wred(acc[j]);
  float sel = 0.f;
#pragma unroll
  for (int j = 0; j < 8; ++j)
    if (lane == j) sel = acc[j];
  if (lane < 8) qW[(bg + lane) * DD + d] = sel + attn_b[d];
}

// ---- scores[b,s] = sum_d v[d]*tanh(qW[b,d]+encWe[b,s,d]) ----
__global__ void scores_k(const float* __restrict__ qW, const float* __restrict__ encWe,
                         const float* __restrict__ attn_v, float* __restrict__ scores) {
  const int lane = threadIdx.x & 63;
  const int wg = (blockIdx.x * blockDim.x + threadIdx.x) >> 6;  // 0..BB*SS-1
  const int b = wg >> 7;
  const int s = wg & 127;
  const float* qb = qW + b * DD;
  const float* ew = encWe + ((size_t)(b * SS + s)) * DD;
  float a = 0.f;
  for (int kb = 0; kb < 16; ++kb) {
    const int dd = kb * 64 + lane;
    a += attn_v[dd] * tanhf(qb[dd] + ew[dd]);
  }
  a = wred(a);
  if (lane == 0) scores[b * SS + s] = a;
}

// ---- softmax over S + weighted sum of enc_out; grid (8, B), 128 thr ----
__global__ void sw_k(const float* __restrict__ scores, const float* __restrict__ enc_out,
                     float* __restrict__ weighted) {
  const int b = blockIdx.y, hc = blockIdx.x, tid = threadIdx.x;
  __shared__ float sa[128];
  __shared__ float red[128];
  const float sc = scores[b * SS + tid];
  red[tid] = sc;
  __syncthreads();
  for (int s = 64; s; s >>= 1) {
    if (tid < s) red[tid] = fmaxf(red[tid], red[tid + s]);
    __syncthreads();
  }
  const float m = red[0];
  __syncthreads();
  const float e = expf(sc - m);
  red[tid] = e;
  __syncthreads();
  for (int s = 64; s; s >>= 1) {
    if (tid < s) red[tid] += red[tid + s];
    __syncthreads();
  }
  const float inv = 1.f / red[0];
  sa[tid] = e * inv;
  __syncthreads();
  const int h = hc * 128 + tid;
  float acc = 0.f;
  for (int s = 0; s < SS; ++s) acc += sa[s] * enc_out[((size_t)(b * SS + s)) * 1024 + h];
  weighted[b * 1024 + h] = acc;
}

// ---- logits[b,o] = out_b[o] + sum_d h1[b,d]*out_w[o,d] -> d_out[b,t,o] ----
__global__ void logits_k(const float* __restrict__ h1, const float* __restrict__ out_w,
                         const float* __restrict__ out_b, float* __restrict__ out, int t) {
  const int lane = threadIdx.x & 63;
  const int o = (blockIdx.x * blockDim.x + threadIdx.x) >> 6;
  if (o >= VO) return;
  float acc[16];
#pragma unroll
  for (int b = 0; b < 16; ++b) acc[b] = 0.f;
  for (int kb = 0; kb < 16; ++kb) {
    const int k = kb * 64 + lane;
    const float wv = out_w[(size_t)o * DD + k];
#pragma unroll
    for (int b = 0; b < 16; ++b) acc[b] = fmaf(wv, h1[b * DD + k], acc[b]);
  }
#pragma unroll
  for (int b = 0; b < 16; ++b) acc[b] = wred(acc[b]);
  float sel = 0.f;
#pragma unroll
  for (int b = 0; b < 16; ++b)
    if (lane == b) sel = acc[b];
  if (lane < 16) out[(size_t)lane * TT * VO + (size_t)t * VO + o] = sel + out_b[o];
}

extern "C" void kernel_launch(void* const* d_in, const int* in_sizes, int n_in,
                              void* d_out, int out_size, void* d_ws, size_t ws_size,
                              hipStream_t stream) {
  const int* x = (const int*)d_in[0];
  const int* gs = (const int*)d_in[1];
  const float* in_emb = (const float*)d_in[2];
  const float* out_emb = (const float*)d_in[3];
  const float* ewih0 = (const float*)d_in[4];
  const float* ewhh0 = (const float*)d_in[5];
  const float* eb0 = (const float*)d_in[6];
  const float* ewih1 = (const float*)d_in[7];
  const float* ewhh1 = (const float*)d_in[8];
  const float* eb1 = (const float*)d_in[9];
  const float* dwih0 = (const float*)d_in[10];
  const float* dwhh0 = (const float*)d_in[11];
  const float* db0 = (const float*)d_in[12];
  const float* dwih1 = (const float*)d_in[13];
  const float* dwhh1 = (const float*)d_in[14];
  const float* db1 = (const float*)d_in[15];
  const float* attn_w = (const float*)d_in[16];
  const float* attn_b = (const float*)d_in[17];
  const float* attn_v = (const float*)d_in[18];
  const float* out_w = (const float*)d_in[19];
  const float* out_b = (const float*)d_in[20];
  float* out = (float*)d_out;

  float* ws = (float*)d_ws;
  size_t off = 0;
  auto alloc = [&](size_t n) { float* p = ws + off; off += n; return p; };
  // state region (memset to zero every call)
  float* h0e = alloc(2 * 2 * BB * HH);
  float* c0e = alloc(2 * BB * HH);
  float* h1e = alloc(2 * 2 * BB * HH);
  float* c1e = alloc(2 * BB * HH);
  float* dh0 = alloc(2 * BB * DD);
  float* dc0 = alloc(BB * DD);
  float* dh1 = alloc(2 * BB * DD);
  float* dc1 = alloc(BB * DD);
  float* zeros = alloc(BB * DD);
  const size_t state_n = off;
  // fully-overwritten buffers
  float* xs_emb = alloc((size_t)SS * BB * EE);
  float* gs_emb = alloc((size_t)TT * BB * EE);
  float* l0 = alloc((size_t)SS * BB * (2 * HH));
  float* enc_out = alloc((size_t)BB * SS * (2 * HH));
  float* encWe = alloc((size_t)BB * SS * DD);
  float* qW = alloc(BB * DD);
  float* scores = alloc(BB * SS);
  float* weighted = alloc(BB * (2 * HH));
  (void)ws_size; (void)in_sizes; (void)n_in; (void)out_size;

  hipMemsetAsync(d_ws, 0, state_n * sizeof(float), stream);

  gather_k<<<dim3(SS, BB), 128, 0, stream>>>(x, in_emb, xs_emb, SS);
  gather_k<<<dim3(TT, BB), 128, 0, stream>>>(gs, out_emb, gs_emb, TT);

  // encoder layer 0 (both dirs per launch)
  int cur = 0;
  for (int t = 0; t < SS; ++t) {
    enc_cell_k<EE><<<dim3(256, 2), 256, 0, stream>>>(
        t, xs_emb, ewih0, ewhh0, eb0, h0e + cur * (2 * BB * HH),
        h0e + (cur ^ 1) * (2 * BB * HH), c0e, l0, BB * 2 * HH, 2 * HH);
    cur ^= 1;
  }
  // encoder layer 1
  cur = 0;
  for (int t = 0; t < SS; ++t) {
    enc_cell_k<2 * HH><<<dim3(256, 2), 256, 0, stream>>>(
        t, l0, ewih1, ewhh1, eb1, h1e + cur * (2 * BB * HH),
        h1e + (cur ^ 1) * (2 * BB * HH), c1e, enc_out, 2 * HH, SS * 2 * HH);
    cur ^= 1;
  }
  // precompute enc_out @ We^T (step-invariant attention term)
  encwe_k<<<32768, 256, 0, stream>>>(enc_out, attn_w, encWe);

  // decoder priming step: zero state, zero input
  int dc = 0;
  dec_cell_k<2 * HH, EE><<<512, 256, 0, stream>>>(
      zeros, zeros, dh0 + dc * BB * DD, dh0 + (dc ^ 1) * BB * DD, dc0, dwih0, dwhh0, db0);
  dec_cell_k<DD, 0><<<512, 256, 0, stream>>>(
      dh0 + (dc ^ 1) * BB * DD, nullptr, dh1 + dc * BB * DD, dh1 + (dc ^ 1) * BB * DD, dc1,
      dwih1, dwhh1, db1);
  dc ^= 1;

  for (int t = 0; t < TT; ++t) {
    qw_k<<<512, 256, 0, stream>>>(dc1, attn_w, attn_b, qW);
    scores_k<<<512, 256, 0, stream>>>(qW, encWe, attn_v, scores);
    sw_k<<<dim3(8, BB), 128, 0, stream>>>(scores, enc_out, weighted);
    const float* emb_prev = (t == 0) ? zeros : (gs_emb + (size_t)(t - 1) * BB * EE);
    dec_cell_k<2 * HH, EE><<<512, 256, 0, stream>>>(
        weighted, emb_prev, dh0 + dc * BB * DD, dh0 + (dc ^ 1) * BB * DD, dc0, dwih0, dwhh0,
        db0);
    dec_cell_k<DD, 0><<<512, 256, 0, stream>>>(
        dh0 + (dc ^ 1) * BB * DD, nullptr, dh1 + dc * BB * DD, dh1 + (dc ^ 1) * BB * DD, dc1,
        dwih1, dwhh1, db1);
    logits_k<<<2500, 256, 0, stream>>>(dh1 + (dc ^ 1) * BB * DD, out_w, out_b, out, t);
    dc ^= 1;
  }
}